// Round 10
// baseline (326.512 us; speedup 1.0000x reference)
//
#include <hip/hip_runtime.h>

#define T_TOK 4096
#define NEXP  8
#define HID   1024
#define INTER 2816
#define CAP   2048

typedef __attribute__((ext_vector_type(8))) short bf16x8;
typedef __attribute__((ext_vector_type(4))) float f32x4;

__device__ __forceinline__ float bf2f(unsigned short u){
  union { unsigned int i; float f; } c; c.i = ((unsigned int)u) << 16; return c.f;
}
__device__ __forceinline__ unsigned short f2bf(float f){
  union { float f; unsigned int i; } c; c.f = f;
  unsigned int x = c.i;
  unsigned int r = (x + 0x7fffu + ((x >> 16) & 1u)) >> 16;
  return (unsigned short)r;
}

__device__ __forceinline__ void gload_lds16(const void* g, void* l){
  __builtin_amdgcn_global_load_lds(
      (const __attribute__((address_space(1))) void*)g,
      (__attribute__((address_space(3))) void*)l, 16, 0, 0);
}

// ---------------- routing: 1 block, 512 threads, wave w owns expert w ----------
__global__ void routing_kernel(const int* __restrict__ eidx,
                               int* __restrict__ assign,   // E*CAP, 0-indexed token (holes -> 0)
                               int* __restrict__ perm,     // T*2, slot index or -1 if dropped
                               int* __restrict__ counts)   // E
{
  int tid = threadIdx.x;
  for (int i = tid; i < NEXP * CAP; i += 512) assign[i] = 0;
  __syncthreads();
  int e = tid >> 6;
  int lane = tid & 63;
  int base = 0;
  for (int t0 = 0; t0 < T_TOK; t0 += 64){
    int t = t0 + lane;
    int i0 = eidx[2*t], i1 = eidx[2*t+1];
    int m = (i0 == e) + (i1 == e);
    int v = m;
    #pragma unroll
    for (int off = 1; off < 64; off <<= 1){
      int u = __shfl_up(v, off);
      if (lane >= off) v += u;
    }
    int pos = base + v;                 // inclusive, 1-indexed
    if (m > 0){
      bool dropped = pos > CAP;
      int slot = dropped ? -1 : (e * CAP + pos - 1);
      if (!dropped) assign[slot] = t;
      if (i0 == e) perm[2*t]   = slot;
      if (i1 == e) perm[2*t+1] = slot;
    }
    base += __shfl(v, 63);
  }
  if (lane == 0) counts[e] = base < CAP ? base : CAP;
}

// ---------------- transpose + cast f32 -> bf16, per-expert (R x Cc) -> (Cc x R) ----
__global__ void transpose_cast(const float* __restrict__ in, unsigned short* __restrict__ out,
                               int R, int Cc)
{
  __shared__ unsigned short tile[64][66];
  int e = blockIdx.z;
  const float* src = in + (size_t)e * R * Cc;
  unsigned short* dst = out + (size_t)e * R * Cc;
  int c0 = blockIdx.x * 64, r0 = blockIdx.y * 64;
  int tr = threadIdx.x >> 4, tc = threadIdx.x & 15;
  #pragma unroll
  for (int it = 0; it < 4; ++it){
    int r = it*16 + tr;
    float4 v = *(const float4*)(src + (size_t)(r0 + r) * Cc + c0 + tc*4);
    tile[r][tc*4+0] = f2bf(v.x);
    tile[r][tc*4+1] = f2bf(v.y);
    tile[r][tc*4+2] = f2bf(v.z);
    tile[r][tc*4+3] = f2bf(v.w);
  }
  __syncthreads();
  #pragma unroll
  for (int it = 0; it < 4; ++it){
    int i = it*16 + tr;
    ushort4 o;
    o.x = tile[tc*4+0][i];
    o.y = tile[tc*4+1][i];
    o.z = tile[tc*4+2][i];
    o.w = tile[tc*4+3][i];
    *(ushort4*)(dst + (size_t)(c0 + i) * R + r0 + tc*4) = o;
  }
}

// ---------------- gather hidden -> x (bf16), one block per slot row ---------------
__global__ void gather_kernel(const float* __restrict__ hidden,
                              const int* __restrict__ assign,
                              unsigned short* __restrict__ x)
{
  int s = blockIdx.x;
  int tok = assign[s];
  int c = threadIdx.x * 4;
  float4 v = *(const float4*)(hidden + (size_t)tok * HID + c);
  ushort4 o; o.x = f2bf(v.x); o.y = f2bf(v.y); o.z = f2bf(v.z); o.w = f2bf(v.w);
  *(ushort4*)(x + (size_t)s * HID + c) = o;
}

// ---------------- grouped GEMM, 128xBN tile, BK=64, 4 waves (2x2) --------------
template<int ROWS>
__device__ __forceinline__ void stage_tile(const unsigned short* gbase, int ldk, int k0,
                                           unsigned short* lds, int lane, int wid){
  #pragma unroll
  for (int c = 0; c < ROWS/32; ++c){
    int rb = c*32 + wid*8;                 // wave-uniform LDS dest
    int row = rb + (lane >> 3);
    int slot = (lane & 7) ^ (row & 7);     // pre-swizzled global source (rule #21)
    const char* src = (const char*)(gbase + (size_t)row * ldk + k0) + slot*16;
    gload_lds16(src, (char*)lds + rb*128);
  }
}

__device__ __forceinline__ bf16x8 lds_frag(const unsigned short* lds, int row, int kslot){
  int slot = kslot ^ (row & 7);            // swizzled read
  return *(const bf16x8*)((const char*)lds + row*128 + slot*16);
}

// GEMM1 (SILU): BN=64 dual-acc -> 64 f32/lane, (256,3), LDS 32KB, 12 waves/CU.
// GEMM2: BN=128 single-acc -> 64 f32/lane, (256,3), LDS 32KB, 12 waves/CU;
//   MFMA:ds_read density 2.0 (vs 1.33 at BN=64), MFMA:gload 4.0 (vs 2.7).
template<bool SILU, int BN>
__global__ __launch_bounds__(256, 3)
void gemm_bf16(const unsigned short* __restrict__ A,    // (E*CAP) x K row-major
               const unsigned short* __restrict__ Bt,   // per-expert (NB x K) row-major (B^T)
               unsigned short* __restrict__ O,          // (E*CAP) x Nout
               const int* __restrict__ counts,
               int K, int Nout)
{
  const int NF = BN / 32;                 // n-fragments per wave (wave N-tile = BN/2)
  int e = blockIdx.z;
  int m0 = blockIdx.y * 128;
  if (m0 >= counts[e]) return;
  int n0 = blockIdx.x * BN;

  __shared__ unsigned short Al[128*64];
  __shared__ unsigned short Bg[BN*64];
  __shared__ unsigned short Bu[SILU ? BN*64 : 64];

  int tid = threadIdx.x;
  int lane = tid & 63, wid = tid >> 6;
  int wm = wid >> 1, wn = wid & 1;
  int lo = lane & 15, hi = lane >> 4;

  size_t bstride = (size_t)(SILU ? 2*INTER : Nout) * K;
  const unsigned short* Ab  = A  + ((size_t)e * CAP + m0) * K;
  const unsigned short* Bgb = Bt + (size_t)e * bstride + (size_t)n0 * K;
  const unsigned short* Bub = Bt + (size_t)e * bstride + (size_t)(INTER + n0) * K;

  f32x4 accg[4][NF] = {};
  f32x4 accu[SILU ? 4 : 1][SILU ? NF : 1] = {};

  for (int k0 = 0; k0 < K; k0 += 64){
    stage_tile<128>(Ab,  K, k0, Al, lane, wid);
    stage_tile<BN>(Bgb, K, k0, Bg, lane, wid);
    if constexpr (SILU) stage_tile<BN>(Bub, K, k0, Bu, lane, wid);
    __syncthreads();   // compiler emits vmcnt(0) drain before barrier
    #pragma unroll
    for (int kk = 0; kk < 64; kk += 32){
      int kslot = (kk >> 3) + hi;
      bf16x8 af[4], bg_[NF], bu_[NF];
      #pragma unroll
      for (int m = 0; m < 4; ++m) af[m] = lds_frag(Al, wm*64 + m*16 + lo, kslot);
      #pragma unroll
      for (int n = 0; n < NF; ++n) bg_[n] = lds_frag(Bg, wn*(BN/2) + n*16 + lo, kslot);
      if constexpr (SILU){
        #pragma unroll
        for (int n = 0; n < NF; ++n) bu_[n] = lds_frag(Bu, wn*(BN/2) + n*16 + lo, kslot);
      }
      #pragma unroll
      for (int m = 0; m < 4; ++m){
        #pragma unroll
        for (int n = 0; n < NF; ++n){
          accg[m][n] = __builtin_amdgcn_mfma_f32_16x16x32_bf16(af[m], bg_[n], accg[m][n], 0, 0, 0);
          if constexpr (SILU)
            accu[m][n] = __builtin_amdgcn_mfma_f32_16x16x32_bf16(af[m], bu_[n], accu[m][n], 0, 0, 0);
        }
      }
    }
    __syncthreads();
  }

  #pragma unroll
  for (int m = 0; m < 4; ++m){
    #pragma unroll
    for (int n = 0; n < NF; ++n){
      int gr = m0 + wm*64 + m*16 + hi*4;
      int gc = n0 + wn*(BN/2) + n*16 + lo;
      #pragma unroll
      for (int j = 0; j < 4; ++j){
        float v;
        if constexpr (SILU){
          float g = accg[m][n][j], u = accu[m][n][j];
          v = g / (1.f + __expf(-g)) * u;
        } else {
          v = accg[m][n][j];
        }
        O[((size_t)e * CAP + gr + j) * Nout + gc] = f2bf(v);
      }
    }
  }
}

// ---------------- combine: out[t] = sum_k w_k * permuted[perm[t,k]] --------------
__global__ void combine_kernel(const unsigned short* __restrict__ permuted,
                               const int* __restrict__ perm,
                               const int* __restrict__ eidx,
                               const float* __restrict__ aff,
                               float* __restrict__ out)
{
  int t = blockIdx.x;
  int i0 = eidx[2*t], i1 = eidx[2*t+1];
  int p0 = perm[2*t], p1 = perm[2*t+1];
  float a0 = (p0 >= 0) ? aff[t*NEXP + i0] : 0.f;
  float a1 = (p1 >= 0) ? aff[t*NEXP + i1] : 0.f;
  float denom = (i0 == i1) ? fabsf(a0) : (fabsf(a0) + fabsf(a1));
  denom = fmaxf(denom, 1e-12f);
  float w0 = a0 / denom, w1 = a1 / denom;
  int s0 = p0 >= 0 ? p0 : 0;
  int s1 = p1 >= 0 ? p1 : 0;
  const unsigned short* r0 = permuted + (size_t)s0 * HID;
  const unsigned short* r1 = permuted + (size_t)s1 * HID;
  int c = threadIdx.x * 4;
  ushort4 v0 = *(const ushort4*)(r0 + c);
  ushort4 v1 = *(const ushort4*)(r1 + c);
  float4 o;
  o.x = w0*bf2f(v0.x) + w1*bf2f(v1.x);
  o.y = w0*bf2f(v0.y) + w1*bf2f(v1.y);
  o.z = w0*bf2f(v0.z) + w1*bf2f(v1.z);
  o.w = w0*bf2f(v0.w) + w1*bf2f(v1.w);
  *(float4*)(out + (size_t)t * HID + c) = o;
}

extern "C" void kernel_launch(void* const* d_in, const int* in_sizes, int n_in,
                              void* d_out, int out_size, void* d_ws, size_t ws_size,
                              hipStream_t stream)
{
  const float* hidden = (const float*)d_in[0];
  const float* aff    = (const float*)d_in[1];
  const int*   eidx   = (const int*)d_in[2];
  const float* wgu    = (const float*)d_in[3];
  const float* wdn    = (const float*)d_in[4];
  float* out = (float*)d_out;

  char* ws = (char*)d_ws;
  // ws layout (bytes):
  //   wt     @ 0          : 92,274,688  (wgu_t bf16; later reused for wd_t)
  //   h      @ 92,274,688 : 92,274,688  (E*CAP x INTER bf16)
  //   x      @184,549,376 : 33,554,432  (E*CAP x HID bf16; reused as `permuted` output)
  //   assign @218,103,808 : 65,536
  //   perm   @218,169,344 : 32,768
  //   counts @218,202,112 : 64          -> total ~208 MiB
  unsigned short* wt     = (unsigned short*)(ws + 0);
  unsigned short* h      = (unsigned short*)(ws + 92274688);
  unsigned short* x      = (unsigned short*)(ws + 184549376);
  int* assign            = (int*)(ws + 218103808);
  int* perm              = (int*)(ws + 218169344);
  int* counts            = (int*)(ws + 218202112);

  routing_kernel<<<1, 512, 0, stream>>>(eidx, assign, perm, counts);
  // w_gate_up: per expert (1024 x 5632) -> (5632 x 1024) bf16
  transpose_cast<<<dim3(88, 16, 8), 256, 0, stream>>>(wgu, wt, HID, 2*INTER);
  gather_kernel<<<dim3(NEXP*CAP), 256, 0, stream>>>(hidden, assign, x);
  // GEMM1 + SiLU*up : h = silu(x @ Wg) * (x @ Wu)  (E*CAP x INTER), 128x64-dual tile
  gemm_bf16<true, 64><<<dim3(44, 16, 8), 256, 0, stream>>>(x, wt, h, counts, HID, INTER);
  // w_down: per expert (2816 x 1024) -> (1024 x 2816) bf16 (overwrites wgu_t)
  transpose_cast<<<dim3(16, 44, 8), 256, 0, stream>>>(wdn, wt, INTER, HID);
  // GEMM2 : permuted = h @ Wd  (E*CAP x HID), written into x buffer, 128x128 tile
  gemm_bf16<false, 128><<<dim3(8, 16, 8), 256, 0, stream>>>(h, wt, x, counts, INTER, HID);
  combine_kernel<<<dim3(T_TOK), 256, 0, stream>>>(x, perm, eidx, aff, out);
}

// Round 12
// 321.493 us; speedup vs baseline: 1.0156x; 1.0156x over previous
//
#include <hip/hip_runtime.h>

#define T_TOK 4096
#define NEXP  8
#define HID   1024
#define INTER 2816
#define CAP   2048

typedef __attribute__((ext_vector_type(8))) short bf16x8;
typedef __attribute__((ext_vector_type(4))) float f32x4;

__device__ __forceinline__ float bf2f(unsigned short u){
  union { unsigned int i; float f; } c; c.i = ((unsigned int)u) << 16; return c.f;
}
__device__ __forceinline__ unsigned short f2bf(float f){
  union { float f; unsigned int i; } c; c.f = f;
  unsigned int x = c.i;
  unsigned int r = (x + 0x7fffu + ((x >> 16) & 1u)) >> 16;
  return (unsigned short)r;
}

__device__ __forceinline__ void gload_lds16(const void* g, void* l){
  __builtin_amdgcn_global_load_lds(
      (const __attribute__((address_space(1))) void*)g,
      (__attribute__((address_space(3))) void*)l, 16, 0, 0);
}

// ---------------- routing: 1 block, 512 threads, wave w owns expert w ----------
__global__ void routing_kernel(const int* __restrict__ eidx,
                               int* __restrict__ assign,   // E*CAP, 0-indexed token (holes -> 0)
                               int* __restrict__ perm,     // T*2, slot index or -1 if dropped
                               int* __restrict__ counts)   // E
{
  int tid = threadIdx.x;
  for (int i = tid; i < NEXP * CAP; i += 512) assign[i] = 0;
  __syncthreads();
  int e = tid >> 6;
  int lane = tid & 63;
  int base = 0;
  for (int t0 = 0; t0 < T_TOK; t0 += 64){
    int t = t0 + lane;
    int i0 = eidx[2*t], i1 = eidx[2*t+1];
    int m = (i0 == e) + (i1 == e);
    int v = m;
    #pragma unroll
    for (int off = 1; off < 64; off <<= 1){
      int u = __shfl_up(v, off);
      if (lane >= off) v += u;
    }
    int pos = base + v;                 // inclusive, 1-indexed
    if (m > 0){
      bool dropped = pos > CAP;
      int slot = dropped ? -1 : (e * CAP + pos - 1);
      if (!dropped) assign[slot] = t;
      if (i0 == e) perm[2*t]   = slot;
      if (i1 == e) perm[2*t+1] = slot;
    }
    base += __shfl(v, 63);
  }
  if (lane == 0) counts[e] = base < CAP ? base : CAP;
}

// ---------------- transpose + cast f32 -> bf16, per-expert (R x Cc) -> (Cc x R) ----
__global__ void transpose_cast(const float* __restrict__ in, unsigned short* __restrict__ out,
                               int R, int Cc)
{
  __shared__ unsigned short tile[64][66];
  int e = blockIdx.z;
  const float* src = in + (size_t)e * R * Cc;
  unsigned short* dst = out + (size_t)e * R * Cc;
  int c0 = blockIdx.x * 64, r0 = blockIdx.y * 64;
  int tr = threadIdx.x >> 4, tc = threadIdx.x & 15;
  #pragma unroll
  for (int it = 0; it < 4; ++it){
    int r = it*16 + tr;
    float4 v = *(const float4*)(src + (size_t)(r0 + r) * Cc + c0 + tc*4);
    tile[r][tc*4+0] = f2bf(v.x);
    tile[r][tc*4+1] = f2bf(v.y);
    tile[r][tc*4+2] = f2bf(v.z);
    tile[r][tc*4+3] = f2bf(v.w);
  }
  __syncthreads();
  #pragma unroll
  for (int it = 0; it < 4; ++it){
    int i = it*16 + tr;
    ushort4 o;
    o.x = tile[tc*4+0][i];
    o.y = tile[tc*4+1][i];
    o.z = tile[tc*4+2][i];
    o.w = tile[tc*4+3][i];
    *(ushort4*)(dst + (size_t)(c0 + i) * R + r0 + tc*4) = o;
  }
}

// ---------------- gather hidden -> x (bf16), one block per slot row ---------------
// Slots >= ceil(counts[e]/128)*128 are never read by any GEMM block (they
// early-exit) nor by combine (perm only points below counts) -> skip them.
__global__ void gather_kernel(const float* __restrict__ hidden,
                              const int* __restrict__ assign,
                              const int* __restrict__ counts,
                              unsigned short* __restrict__ x)
{
  int s = blockIdx.x;
  int e = s / CAP, local = s % CAP;
  if (local >= ((counts[e] + 127) & ~127)) return;
  int tok = assign[s];
  int c = threadIdx.x * 4;
  float4 v = *(const float4*)(hidden + (size_t)tok * HID + c);
  ushort4 o; o.x = f2bf(v.x); o.y = f2bf(v.y); o.z = f2bf(v.z); o.w = f2bf(v.w);
  *(ushort4*)(x + (size_t)s * HID + c) = o;
}

// ---------------- grouped GEMM, 128xBN tile, BK=64, 4 waves (2x2) --------------
template<int ROWS>
__device__ __forceinline__ void stage_tile(const unsigned short* gbase, int ldk, int k0,
                                           unsigned short* lds, int lane, int wid){
  #pragma unroll
  for (int c = 0; c < ROWS/32; ++c){
    int rb = c*32 + wid*8;                 // wave-uniform LDS dest
    int row = rb + (lane >> 3);
    int slot = (lane & 7) ^ (row & 7);     // pre-swizzled global source (rule #21)
    const char* src = (const char*)(gbase + (size_t)row * ldk + k0) + slot*16;
    gload_lds16(src, (char*)lds + rb*128);
  }
}

__device__ __forceinline__ bf16x8 lds_frag(const unsigned short* lds, int row, int kslot){
  int slot = kslot ^ (row & 7);            // swizzled read
  return *(const bf16x8*)((const char*)lds + row*128 + slot*16);
}

// Both GEMMs: acc 64 f32/lane + ~64 arch VGPR (R10 CSV) ~= 128 unified = the
// exact (256,4) budget; LDS 32KB x 4 = 128KB <= 160. 16 waves/CU target.
// Spill sentinel: WRITE_SIZE >> expected + VGPR_Count drop -> revert to 3.
template<bool SILU, int BN>
__global__ __launch_bounds__(256, 4)
void gemm_bf16(const unsigned short* __restrict__ A,    // (E*CAP) x K row-major
               const unsigned short* __restrict__ Bt,   // per-expert (NB x K) row-major (B^T)
               unsigned short* __restrict__ O,          // (E*CAP) x Nout
               const int* __restrict__ counts,
               int K, int Nout)
{
  const int NF = BN / 32;                 // n-fragments per wave (wave N-tile = BN/2)
  int e = blockIdx.z;
  int m0 = blockIdx.y * 128;
  if (m0 >= counts[e]) return;
  int n0 = blockIdx.x * BN;

  __shared__ unsigned short Al[128*64];
  __shared__ unsigned short Bg[BN*64];
  __shared__ unsigned short Bu[SILU ? BN*64 : 64];

  int tid = threadIdx.x;
  int lane = tid & 63, wid = tid >> 6;
  int wm = wid >> 1, wn = wid & 1;
  int lo = lane & 15, hi = lane >> 4;

  size_t bstride = (size_t)(SILU ? 2*INTER : Nout) * K;
  const unsigned short* Ab  = A  + ((size_t)e * CAP + m0) * K;
  const unsigned short* Bgb = Bt + (size_t)e * bstride + (size_t)n0 * K;
  const unsigned short* Bub = Bt + (size_t)e * bstride + (size_t)(INTER + n0) * K;

  f32x4 accg[4][NF] = {};
  f32x4 accu[SILU ? 4 : 1][SILU ? NF : 1] = {};

  for (int k0 = 0; k0 < K; k0 += 64){
    stage_tile<128>(Ab,  K, k0, Al, lane, wid);
    stage_tile<BN>(Bgb, K, k0, Bg, lane, wid);
    if constexpr (SILU) stage_tile<BN>(Bub, K, k0, Bu, lane, wid);
    __syncthreads();   // compiler emits vmcnt(0) drain before barrier
    #pragma unroll
    for (int kk = 0; kk < 64; kk += 32){
      int kslot = (kk >> 3) + hi;
      bf16x8 af[4], bg_[NF], bu_[NF];
      #pragma unroll
      for (int m = 0; m < 4; ++m) af[m] = lds_frag(Al, wm*64 + m*16 + lo, kslot);
      #pragma unroll
      for (int n = 0; n < NF; ++n) bg_[n] = lds_frag(Bg, wn*(BN/2) + n*16 + lo, kslot);
      if constexpr (SILU){
        #pragma unroll
        for (int n = 0; n < NF; ++n) bu_[n] = lds_frag(Bu, wn*(BN/2) + n*16 + lo, kslot);
      }
      #pragma unroll
      for (int m = 0; m < 4; ++m){
        #pragma unroll
        for (int n = 0; n < NF; ++n){
          accg[m][n] = __builtin_amdgcn_mfma_f32_16x16x32_bf16(af[m], bg_[n], accg[m][n], 0, 0, 0);
          if constexpr (SILU)
            accu[m][n] = __builtin_amdgcn_mfma_f32_16x16x32_bf16(af[m], bu_[n], accu[m][n], 0, 0, 0);
        }
      }
    }
    __syncthreads();
  }

  #pragma unroll
  for (int m = 0; m < 4; ++m){
    #pragma unroll
    for (int n = 0; n < NF; ++n){
      int gr = m0 + wm*64 + m*16 + hi*4;
      int gc = n0 + wn*(BN/2) + n*16 + lo;
      #pragma unroll
      for (int j = 0; j < 4; ++j){
        float v;
        if constexpr (SILU){
          float g = accg[m][n][j], u = accu[m][n][j];
          v = g / (1.f + __expf(-g)) * u;
        } else {
          v = accg[m][n][j];
        }
        O[((size_t)e * CAP + gr + j) * Nout + gc] = f2bf(v);
      }
    }
  }
}

// ---------------- combine: out[t] = sum_k w_k * permuted[perm[t,k]] --------------
__global__ void combine_kernel(const unsigned short* __restrict__ permuted,
                               const int* __restrict__ perm,
                               const int* __restrict__ eidx,
                               const float* __restrict__ aff,
                               float* __restrict__ out)
{
  int t = blockIdx.x;
  int i0 = eidx[2*t], i1 = eidx[2*t+1];
  int p0 = perm[2*t], p1 = perm[2*t+1];
  float a0 = (p0 >= 0) ? aff[t*NEXP + i0] : 0.f;
  float a1 = (p1 >= 0) ? aff[t*NEXP + i1] : 0.f;
  float denom = (i0 == i1) ? fabsf(a0) : (fabsf(a0) + fabsf(a1));
  denom = fmaxf(denom, 1e-12f);
  float w0 = a0 / denom, w1 = a1 / denom;
  int s0 = p0 >= 0 ? p0 : 0;
  int s1 = p1 >= 0 ? p1 : 0;
  const unsigned short* r0 = permuted + (size_t)s0 * HID;
  const unsigned short* r1 = permuted + (size_t)s1 * HID;
  int c = threadIdx.x * 4;
  ushort4 v0 = *(const ushort4*)(r0 + c);
  ushort4 v1 = *(const ushort4*)(r1 + c);
  float4 o;
  o.x = w0*bf2f(v0.x) + w1*bf2f(v1.x);
  o.y = w0*bf2f(v0.y) + w1*bf2f(v1.y);
  o.z = w0*bf2f(v0.z) + w1*bf2f(v1.z);
  o.w = w0*bf2f(v0.w) + w1*bf2f(v1.w);
  *(float4*)(out + (size_t)t * HID + c) = o;
}

extern "C" void kernel_launch(void* const* d_in, const int* in_sizes, int n_in,
                              void* d_out, int out_size, void* d_ws, size_t ws_size,
                              hipStream_t stream)
{
  const float* hidden = (const float*)d_in[0];
  const float* aff    = (const float*)d_in[1];
  const int*   eidx   = (const int*)d_in[2];
  const float* wgu    = (const float*)d_in[3];
  const float* wdn    = (const float*)d_in[4];
  float* out = (float*)d_out;

  char* ws = (char*)d_ws;
  // ws layout (bytes):
  //   wt     @ 0          : 92,274,688  (wgu_t bf16; later reused for wd_t)
  //   h      @ 92,274,688 : 92,274,688  (E*CAP x INTER bf16)
  //   x      @184,549,376 : 33,554,432  (E*CAP x HID bf16; reused as `permuted` output)
  //   assign @218,103,808 : 65,536
  //   perm   @218,169,344 : 32,768
  //   counts @218,202,112 : 64          -> total ~208 MiB
  unsigned short* wt     = (unsigned short*)(ws + 0);
  unsigned short* h      = (unsigned short*)(ws + 92274688);
  unsigned short* x      = (unsigned short*)(ws + 184549376);
  int* assign            = (int*)(ws + 218103808);
  int* perm              = (int*)(ws + 218169344);
  int* counts            = (int*)(ws + 218202112);

  routing_kernel<<<1, 512, 0, stream>>>(eidx, assign, perm, counts);
  // w_gate_up: per expert (1024 x 5632) -> (5632 x 1024) bf16
  transpose_cast<<<dim3(88, 16, 8), 256, 0, stream>>>(wgu, wt, HID, 2*INTER);
  gather_kernel<<<dim3(NEXP*CAP), 256, 0, stream>>>(hidden, assign, counts, x);
  // GEMM1 + SiLU*up : h = silu(x @ Wg) * (x @ Wu)  (E*CAP x INTER), 128x64-dual tile
  gemm_bf16<true, 64><<<dim3(44, 16, 8), 256, 0, stream>>>(x, wt, h, counts, HID, INTER);
  // w_down: per expert (2816 x 1024) -> (1024 x 2816) bf16 (overwrites wgu_t)
  transpose_cast<<<dim3(16, 44, 8), 256, 0, stream>>>(wdn, wt, INTER, HID);
  // GEMM2 : permuted = h @ Wd  (E*CAP x HID), written into x buffer, 128x128 tile
  gemm_bf16<false, 128><<<dim3(8, 16, 8), 256, 0, stream>>>(h, wt, x, counts, INTER, HID);
  combine_kernel<<<dim3(T_TOK), 256, 0, stream>>>(x, perm, eidx, aff, out);
}

// Round 13
// 306.238 us; speedup vs baseline: 1.0662x; 1.0498x over previous
//
#include <hip/hip_runtime.h>

#define T_TOK 4096
#define NEXP  8
#define HID   1024
#define INTER 2816
#define CAP   2048

typedef __attribute__((ext_vector_type(8))) short bf16x8;
typedef __attribute__((ext_vector_type(4))) float f32x4;

__device__ __forceinline__ float bf2f(unsigned short u){
  union { unsigned int i; float f; } c; c.i = ((unsigned int)u) << 16; return c.f;
}
__device__ __forceinline__ unsigned short f2bf(float f){
  union { float f; unsigned int i; } c; c.f = f;
  unsigned int x = c.i;
  unsigned int r = (x + 0x7fffu + ((x >> 16) & 1u)) >> 16;
  return (unsigned short)r;
}

__device__ __forceinline__ void gload_lds16(const void* g, void* l){
  __builtin_amdgcn_global_load_lds(
      (const __attribute__((address_space(1))) void*)g,
      (__attribute__((address_space(3))) void*)l, 16, 0, 0);
}

// ---------------- routing: 1 block, 512 threads, wave w owns expert w ----------
__global__ void routing_kernel(const int* __restrict__ eidx,
                               int* __restrict__ assign,   // E*CAP, 0-indexed token (holes -> 0)
                               int* __restrict__ perm,     // T*2, slot index or -1 if dropped
                               int* __restrict__ counts)   // E
{
  int tid = threadIdx.x;
  for (int i = tid; i < NEXP * CAP; i += 512) assign[i] = 0;
  __syncthreads();
  int e = tid >> 6;
  int lane = tid & 63;
  int base = 0;
  for (int t0 = 0; t0 < T_TOK; t0 += 64){
    int t = t0 + lane;
    int i0 = eidx[2*t], i1 = eidx[2*t+1];
    int m = (i0 == e) + (i1 == e);
    int v = m;
    #pragma unroll
    for (int off = 1; off < 64; off <<= 1){
      int u = __shfl_up(v, off);
      if (lane >= off) v += u;
    }
    int pos = base + v;                 // inclusive, 1-indexed
    if (m > 0){
      bool dropped = pos > CAP;
      int slot = dropped ? -1 : (e * CAP + pos - 1);
      if (!dropped) assign[slot] = t;
      if (i0 == e) perm[2*t]   = slot;
      if (i1 == e) perm[2*t+1] = slot;
    }
    base += __shfl(v, 63);
  }
  if (lane == 0) counts[e] = base < CAP ? base : CAP;
}

// ---------------- transpose + cast f32 -> bf16, per-expert (R x Cc) -> (Cc x R) ----
__global__ void transpose_cast(const float* __restrict__ in, unsigned short* __restrict__ out,
                               int R, int Cc)
{
  __shared__ unsigned short tile[64][66];
  int e = blockIdx.z;
  const float* src = in + (size_t)e * R * Cc;
  unsigned short* dst = out + (size_t)e * R * Cc;
  int c0 = blockIdx.x * 64, r0 = blockIdx.y * 64;
  int tr = threadIdx.x >> 4, tc = threadIdx.x & 15;
  #pragma unroll
  for (int it = 0; it < 4; ++it){
    int r = it*16 + tr;
    float4 v = *(const float4*)(src + (size_t)(r0 + r) * Cc + c0 + tc*4);
    tile[r][tc*4+0] = f2bf(v.x);
    tile[r][tc*4+1] = f2bf(v.y);
    tile[r][tc*4+2] = f2bf(v.z);
    tile[r][tc*4+3] = f2bf(v.w);
  }
  __syncthreads();
  #pragma unroll
  for (int it = 0; it < 4; ++it){
    int i = it*16 + tr;
    ushort4 o;
    o.x = tile[tc*4+0][i];
    o.y = tile[tc*4+1][i];
    o.z = tile[tc*4+2][i];
    o.w = tile[tc*4+3][i];
    *(ushort4*)(dst + (size_t)(c0 + i) * R + r0 + tc*4) = o;
  }
}

// ---------------- gather hidden -> x (bf16), one block per slot row ---------------
__global__ void gather_kernel(const float* __restrict__ hidden,
                              const int* __restrict__ assign,
                              const int* __restrict__ counts,
                              unsigned short* __restrict__ x)
{
  int s = blockIdx.x;
  int e = s / CAP, local = s % CAP;
  if (local >= ((counts[e] + 127) & ~127)) return;
  int tok = assign[s];
  int c = threadIdx.x * 4;
  float4 v = *(const float4*)(hidden + (size_t)tok * HID + c);
  ushort4 o; o.x = f2bf(v.x); o.y = f2bf(v.y); o.z = f2bf(v.z); o.w = f2bf(v.w);
  *(ushort4*)(x + (size_t)s * HID + c) = o;
}

// ---------------- grouped GEMM, 128xBN tile, BK=64, 4 waves (2x2) --------------
template<int ROWS>
__device__ __forceinline__ void stage_tile(const unsigned short* gbase, int ldk, int k0,
                                           unsigned short* lds, int lane, int wid){
  #pragma unroll
  for (int c = 0; c < ROWS/32; ++c){
    int rb = c*32 + wid*8;                 // wave-uniform LDS dest
    int row = rb + (lane >> 3);
    int slot = (lane & 7) ^ (row & 7);     // pre-swizzled global source (rule #21)
    const char* src = (const char*)(gbase + (size_t)row * ldk + k0) + slot*16;
    gload_lds16(src, (char*)lds + rb*128);
  }
}

__device__ __forceinline__ bf16x8 lds_frag(const unsigned short* lds, int row, int kslot){
  int slot = kslot ^ (row & 7);            // swizzled read
  return *(const bf16x8*)((const char*)lds + row*128 + slot*16);
}

// KSPLIT-way split-K: blockIdx.z = e*KSPLIT + kc; kc==0 -> O, kc==1 -> O2 (bf16
// partials, summed in combine). GEMM2 was grid-starved at 536 blocks (2.1/CU,
// MfmaUtil 17.6%); KSPLIT=2 doubles blocks to match the (256,4) residency cap.
template<bool SILU, int BN, int KSPLIT>
__global__ __launch_bounds__(256, 4)
void gemm_bf16(const unsigned short* __restrict__ A,    // (E*CAP) x K row-major
               const unsigned short* __restrict__ Bt,   // per-expert (NB x K) row-major (B^T)
               unsigned short* __restrict__ O,          // (E*CAP) x Nout
               unsigned short* __restrict__ O2,         // partial #2 (KSPLIT=2 only)
               const int* __restrict__ counts,
               int K, int Nout)
{
  const int NF = BN / 32;                 // n-fragments per wave (wave N-tile = BN/2)
  int z = blockIdx.z;
  int e = z / KSPLIT, kc = z % KSPLIT;
  int m0 = blockIdx.y * 128;
  if (m0 >= counts[e]) return;
  int n0 = blockIdx.x * BN;
  int klen = K / KSPLIT;
  int kbase = kc * klen;
  unsigned short* Op = (KSPLIT == 2 && kc == 1) ? O2 : O;

  __shared__ unsigned short Al[128*64];
  __shared__ unsigned short Bg[BN*64];
  __shared__ unsigned short Bu[SILU ? BN*64 : 64];

  int tid = threadIdx.x;
  int lane = tid & 63, wid = tid >> 6;
  int wm = wid >> 1, wn = wid & 1;
  int lo = lane & 15, hi = lane >> 4;

  size_t bstride = (size_t)(SILU ? 2*INTER : Nout) * K;
  const unsigned short* Ab  = A  + ((size_t)e * CAP + m0) * K;
  const unsigned short* Bgb = Bt + (size_t)e * bstride + (size_t)n0 * K;
  const unsigned short* Bub = Bt + (size_t)e * bstride + (size_t)(INTER + n0) * K;

  f32x4 accg[4][NF] = {};
  f32x4 accu[SILU ? 4 : 1][SILU ? NF : 1] = {};

  for (int k0 = kbase; k0 < kbase + klen; k0 += 64){
    stage_tile<128>(Ab,  K, k0, Al, lane, wid);
    stage_tile<BN>(Bgb, K, k0, Bg, lane, wid);
    if constexpr (SILU) stage_tile<BN>(Bub, K, k0, Bu, lane, wid);
    __syncthreads();   // compiler emits vmcnt(0) drain before barrier
    #pragma unroll
    for (int kk = 0; kk < 64; kk += 32){
      int kslot = (kk >> 3) + hi;
      bf16x8 af[4], bg_[NF], bu_[NF];
      #pragma unroll
      for (int m = 0; m < 4; ++m) af[m] = lds_frag(Al, wm*64 + m*16 + lo, kslot);
      #pragma unroll
      for (int n = 0; n < NF; ++n) bg_[n] = lds_frag(Bg, wn*(BN/2) + n*16 + lo, kslot);
      if constexpr (SILU){
        #pragma unroll
        for (int n = 0; n < NF; ++n) bu_[n] = lds_frag(Bu, wn*(BN/2) + n*16 + lo, kslot);
      }
      #pragma unroll
      for (int m = 0; m < 4; ++m){
        #pragma unroll
        for (int n = 0; n < NF; ++n){
          accg[m][n] = __builtin_amdgcn_mfma_f32_16x16x32_bf16(af[m], bg_[n], accg[m][n], 0, 0, 0);
          if constexpr (SILU)
            accu[m][n] = __builtin_amdgcn_mfma_f32_16x16x32_bf16(af[m], bu_[n], accu[m][n], 0, 0, 0);
        }
      }
    }
    __syncthreads();
  }

  #pragma unroll
  for (int m = 0; m < 4; ++m){
    #pragma unroll
    for (int n = 0; n < NF; ++n){
      int gr = m0 + wm*64 + m*16 + hi*4;
      int gc = n0 + wn*(BN/2) + n*16 + lo;
      #pragma unroll
      for (int j = 0; j < 4; ++j){
        float v;
        if constexpr (SILU){
          float g = accg[m][n][j], u = accu[m][n][j];
          v = g / (1.f + __expf(-g)) * u;
        } else {
          v = accg[m][n][j];
        }
        Op[((size_t)e * CAP + gr + j) * Nout + gc] = f2bf(v);
      }
    }
  }
}

// ---------------- combine: out[t] = sum_k w_k * (P0+P1)[perm[t,k]] --------------
__global__ void combine_kernel(const unsigned short* __restrict__ p0,
                               const unsigned short* __restrict__ p1,
                               const int* __restrict__ perm,
                               const int* __restrict__ eidx,
                               const float* __restrict__ aff,
                               float* __restrict__ out)
{
  int t = blockIdx.x;
  int i0 = eidx[2*t], i1 = eidx[2*t+1];
  int q0 = perm[2*t], q1 = perm[2*t+1];
  float a0 = (q0 >= 0) ? aff[t*NEXP + i0] : 0.f;
  float a1 = (q1 >= 0) ? aff[t*NEXP + i1] : 0.f;
  float denom = (i0 == i1) ? fabsf(a0) : (fabsf(a0) + fabsf(a1));
  denom = fmaxf(denom, 1e-12f);
  float w0 = a0 / denom, w1 = a1 / denom;
  size_t s0 = (size_t)(q0 >= 0 ? q0 : 0) * HID;
  size_t s1 = (size_t)(q1 >= 0 ? q1 : 0) * HID;
  int c = threadIdx.x * 4;
  ushort4 v0a = *(const ushort4*)(p0 + s0 + c);
  ushort4 v0b = *(const ushort4*)(p1 + s0 + c);
  ushort4 v1a = *(const ushort4*)(p0 + s1 + c);
  ushort4 v1b = *(const ushort4*)(p1 + s1 + c);
  float4 o;
  o.x = w0*(bf2f(v0a.x)+bf2f(v0b.x)) + w1*(bf2f(v1a.x)+bf2f(v1b.x));
  o.y = w0*(bf2f(v0a.y)+bf2f(v0b.y)) + w1*(bf2f(v1a.y)+bf2f(v1b.y));
  o.z = w0*(bf2f(v0a.z)+bf2f(v0b.z)) + w1*(bf2f(v1a.z)+bf2f(v1b.z));
  o.w = w0*(bf2f(v0a.w)+bf2f(v0b.w)) + w1*(bf2f(v1a.w)+bf2f(v1b.w));
  *(float4*)(out + (size_t)t * HID + c) = o;
}

extern "C" void kernel_launch(void* const* d_in, const int* in_sizes, int n_in,
                              void* d_out, int out_size, void* d_ws, size_t ws_size,
                              hipStream_t stream)
{
  const float* hidden = (const float*)d_in[0];
  const float* aff    = (const float*)d_in[1];
  const int*   eidx   = (const int*)d_in[2];
  const float* wgu    = (const float*)d_in[3];
  const float* wdn    = (const float*)d_in[4];
  float* out = (float*)d_out;

  char* ws = (char*)d_ws;
  // ws layout (bytes), total ~208 MiB (unchanged):
  //   wt @ 0            : 92,274,688  (wgu_t bf16 for GEMM1; then wd_t = 46,137,344
  //                                    for GEMM2, whose upper half hosts P1)
  //   p1 @ 46,137,344   : 33,554,432  (GEMM2 kc=1 bf16 partial — inside wt region,
  //                                    above wd_t; written after wgu_t is dead)
  //   h  @ 92,274,688   : 92,274,688  (E*CAP x INTER bf16)
  //   x  @184,549,376   : 33,554,432  (gather out; then GEMM2 kc=0 partial P0)
  //   assign @218,103,808 / perm @218,169,344 / counts @218,202,112
  unsigned short* wt     = (unsigned short*)(ws + 0);
  unsigned short* p1     = (unsigned short*)(ws + 46137344);
  unsigned short* h      = (unsigned short*)(ws + 92274688);
  unsigned short* x      = (unsigned short*)(ws + 184549376);
  int* assign            = (int*)(ws + 218103808);
  int* perm              = (int*)(ws + 218169344);
  int* counts            = (int*)(ws + 218202112);

  routing_kernel<<<1, 512, 0, stream>>>(eidx, assign, perm, counts);
  // w_gate_up: per expert (1024 x 5632) -> (5632 x 1024) bf16
  transpose_cast<<<dim3(88, 16, 8), 256, 0, stream>>>(wgu, wt, HID, 2*INTER);
  gather_kernel<<<dim3(NEXP*CAP), 256, 0, stream>>>(hidden, assign, counts, x);
  // GEMM1 + SiLU*up : h = silu(x @ Wg) * (x @ Wu)  (E*CAP x INTER), 128x64-dual
  gemm_bf16<true, 64, 1><<<dim3(44, 16, 8), 256, 0, stream>>>(x, wt, h, nullptr, counts, HID, INTER);
  // w_down: per expert (2816 x 1024) -> (1024 x 2816) bf16 (lower 46.1MB of wt)
  transpose_cast<<<dim3(16, 44, 8), 256, 0, stream>>>(wdn, wt, INTER, HID);
  // GEMM2 split-K=2: P0 (x region) + P1; 1072 active blocks vs 536
  gemm_bf16<false, 128, 2><<<dim3(8, 16, 16), 256, 0, stream>>>(h, wt, x, p1, counts, INTER, HID);
  combine_kernel<<<dim3(T_TOK), 256, 0, stream>>>(x, p1, perm, eidx, aff, out);
}